// Round 13
// baseline (212.189 us; speedup 1.0000x reference)
//
#include <hip/hip_runtime.h>
#include <hip/hip_bf16.h>
#include <math.h>

#define NN 2048
#define CC 512
#define NEDGE 65536

typedef __hip_bfloat16 bf16;
typedef __attribute__((ext_vector_type(8))) short short8;
typedef __attribute__((ext_vector_type(4))) float floatx4;

static constexpr float TWO_PI_F = 6.2831853071795864769f;

// async global->LDS direct copy, 16 B per lane (dest = wave-uniform base + lane*16)
__device__ __forceinline__ void gld16(const void* g, void* l) {
    __builtin_amdgcn_global_load_lds(
        (const __attribute__((address_space(1))) unsigned int*)(unsigned long long)(uintptr_t)g,
        (__attribute__((address_space(3))) unsigned int*)(unsigned long long)(uintptr_t)l,
        16, 0, 0);
}

// ---------------- detector + colsum zero ----------------
__global__ __launch_bounds__(256) void detect_k(const unsigned int* __restrict__ qword,
                                                const unsigned int* __restrict__ ewords,
                                                int* __restrict__ flag,
                                                float* __restrict__ colsum) {
    int tid = threadIdx.x;
#pragma unroll
    for (int i = 0; i < 8; ++i) colsum[tid * 8 + i] = 0.f;
    if (tid < 64) {
        unsigned int w0 = ewords[2 * tid + 1];
        unsigned int w1 = ewords[128 + 2 * tid + 1];
        unsigned long long b = __ballot((w0 | w1) != 0u);
        if (tid == 0) {
            flag[0] = ((qword[0] & 0xFFFFu) == 0x3E80u) ? 1 : 0;
            flag[1] = (b == 0ull) ? 1 : 0;
        }
    }
}

// ---------------- prep kernels ----------------

__global__ void scatter_edges_k(const void* __restrict__ edges,
                                const void* __restrict__ w,
                                float* __restrict__ A,
                                const int* __restrict__ flag) {
    int e = blockIdx.x * 256 + threadIdx.x;
    if (e >= NEDGE) return;
    int f, t;
    if (flag[1]) {
        f = (int)((const long long*)edges)[e];
        t = (int)((const long long*)edges)[NEDGE + e];
    } else {
        f = ((const int*)edges)[e];
        t = ((const int*)edges)[NEDGE + e];
    }
    float wv = flag[0] ? __bfloat162float(((const bf16*)w)[e]) : ((const float*)w)[e];
    f &= (NN - 1); t &= (NN - 1);
    atomicAdd(&A[(size_t)f * NN + t], wv);
}

// Fused row+col sums. Blocks 0..2047: rowsum[i] (atomic-free LDS reduce).
// Blocks 2048..2303: 64-row col-stripe partials (8192 atomics, 4/address).
__global__ void sums_k(const float* __restrict__ A,
                       float* __restrict__ rowsum, float* __restrict__ colsum) {
    int b = blockIdx.x;
    if (b < NN) {
        float s = 0.f;
        for (int j = threadIdx.x; j < NN; j += 256) s += A[(size_t)b * NN + j];
        __shared__ float red[256];
        red[threadIdx.x] = s;
        __syncthreads();
        for (int off = 128; off > 0; off >>= 1) {
            if (threadIdx.x < off) red[threadIdx.x] += red[threadIdx.x + off];
            __syncthreads();
        }
        if (threadIdx.x == 0) rowsum[b] = red[0];
    } else {
        int bb = b - NN;                       // 0..255
        int col = (bb & 7) * 256 + threadIdx.x;
        int r0 = (bb >> 3) * 64;
        float s = 0.f;
        for (int r = r0; r < r0 + 64; ++r) s += A[(size_t)r * NN + col];
        atomicAdd(&colsum[col], s);
    }
}

// Mpack[i][j] = bf16(-cos(th)*A_norm), Mpack[i][2048+j] = bf16(sin(th)*A_norm)
__global__ __launch_bounds__(1024) void build_Mpack_k(
    const float* __restrict__ A,
    const float* __restrict__ rowsum, const float* __restrict__ colsum,
    const void* __restrict__ qp, bf16* __restrict__ Mpack,
    const int* __restrict__ flag) {
    __shared__ float tmir[32][33];
    int tx = threadIdx.x, ty = threadIdx.y;
    int j0 = blockIdx.x * 32, i0 = blockIdx.y * 32;
    tmir[ty][tx] = A[(size_t)(j0 + ty) * NN + i0 + tx];
    __syncthreads();
    int i = i0 + ty, j = j0 + tx;
    float qv = flag[0] ? __bfloat162float(((const bf16*)qp)[0]) : ((const float*)qp)[0];
    float di = 0.5f * (rowsum[i] + colsum[i]); di = (di == 0.f) ? 1.f : di;
    float dj = 0.5f * (rowsum[j] + colsum[j]); dj = (dj == 0.f) ? 1.f : dj;
    float a = A[(size_t)i * NN + j];
    float b = tmir[tx][ty];              // A[j][i]
    float an = rsqrtf(di) * (0.5f * (a + b)) * rsqrtf(dj);
    float th = TWO_PI_F * qv * (a - b);
    float sn, cs;
    sincosf(th, &sn, &cs);
    Mpack[(size_t)i * (2 * NN) + j]      = __float2bfloat16(-cs * an);
    Mpack[(size_t)i * (2 * NN) + NN + j] = __float2bfloat16(sn * an);
}

// Fused input pack: blocks 0..1023 = convert_X_BT (Af seg0 + BT X-pack);
// blocks 1024..1791 = WT transpose. Branch is block-uniform.
__global__ __launch_bounds__(1024) void pack_inputs_k(
    const void* __restrict__ xr, const void* __restrict__ xi,
    const void* __restrict__ Wt,
    bf16* __restrict__ Af, bf16* __restrict__ BT, bf16* __restrict__ WT,
    const int* __restrict__ flag) {
    __shared__ float t1[32][33];
    __shared__ float t2[32][33];
    int tid = threadIdx.x;
    int tx = tid & 31, ty = tid >> 5;
    int bx = blockIdx.x;
    int isbf = flag[0];
    if (bx < 1024) {
        int c0 = (bx & 15) * 32, r0 = (bx >> 4) * 32;
        size_t sidx = (size_t)(r0 + ty) * CC + c0 + tx;
        float fr, fi;
        if (isbf) {
            fr = __bfloat162float(((const bf16*)xr)[sidx]);
            fi = __bfloat162float(((const bf16*)xi)[sidx]);
        } else {
            fr = ((const float*)xr)[sidx];
            fi = ((const float*)xi)[sidx];
        }
        int r = r0 + ty, c = c0 + tx;
        Af[(size_t)r * 1536 + c]        = __float2bfloat16(-fi);
        Af[(size_t)(NN + r) * 1536 + c] = __float2bfloat16(fr);
        t1[ty][tx] = fr;
        t2[ty][tx] = fi;
        __syncthreads();
        float xrt = t1[tx][ty];   // Xr[r0+tx][c0+ty]
        float xit = t2[tx][ty];
        int n = c0 + ty, k = r0 + tx;
        BT[(size_t)n * 4096 + k]                = __float2bfloat16(xrt);
        BT[(size_t)(512 + n) * 4096 + k]        = __float2bfloat16(xit);
        BT[(size_t)n * 4096 + 2048 + k]         = __float2bfloat16(-xit);
        BT[(size_t)(512 + n) * 4096 + 2048 + k] = __float2bfloat16(xrt);
    } else {
        int bw = bx - 1024;               // 0..767
        int k0 = (bw % 48) * 32, o0 = (bw / 48) * 32;
        size_t sidx = (size_t)(k0 + ty) * CC + o0 + tx;
        t1[ty][tx] = isbf ? __bfloat162float(((const bf16*)Wt)[sidx])
                          : ((const float*)Wt)[sidx];
        __syncthreads();
        WT[(size_t)(o0 + ty) * 1536 + k0 + tx] = __float2bfloat16(t1[tx][ty]);
    }
}

// Fused PT consumer: sum 8 bf16 partials of PT [1024][2048], emit BT (G2 B-operand)
// and Af seg1. Grid (2048/32, 512/32), block (32,32).
__global__ __launch_bounds__(1024) void packPT_k(const bf16* __restrict__ Pb,
                                                 bf16* __restrict__ BT,
                                                 bf16* __restrict__ Af) {
    __shared__ float t1[32][33];
    __shared__ float t2[32][33];
    int tx = threadIdx.x, ty = threadIdx.y;
    int k0 = blockIdx.x * 32, n0 = blockIdx.y * 32;   // n0 in [0,512)
    size_t i1 = (size_t)(n0 + ty) * 2048 + k0 + tx;
    size_t i2 = (size_t)(512 + n0 + ty) * 2048 + k0 + tx;
    float s1 = 0.f, s2 = 0.f;
#pragma unroll
    for (int z = 0; z < 8; ++z) {
        s1 += __bfloat162float(Pb[(size_t)z * 1024 * 2048 + i1]);
        s2 += __bfloat162float(Pb[(size_t)z * 1024 * 2048 + i2]);
    }
    t1[ty][tx] = s1;
    t2[ty][tx] = s2;
    BT[(size_t)(n0 + ty) * 4096 + k0 + tx]              = __float2bfloat16(s1);
    BT[(size_t)(n0 + ty) * 4096 + 2048 + k0 + tx]       = __float2bfloat16(-s2);
    BT[(size_t)(512 + n0 + ty) * 4096 + k0 + tx]        = __float2bfloat16(s2);
    BT[(size_t)(512 + n0 + ty) * 4096 + 2048 + k0 + tx] = __float2bfloat16(s1);
    __syncthreads();
    Af[(size_t)(k0 + ty) * 1536 + 512 + n0 + tx]        = __float2bfloat16(-t2[tx][ty]);
    Af[(size_t)(NN + k0 + ty) * 1536 + 512 + n0 + tx]   = __float2bfloat16(t1[tx][ty]);
}

// Af seg2 = 2*sum(8 partials) - X (reads X inputs directly)
__global__ void epi2_k(const bf16* __restrict__ Pb,
                       const void* __restrict__ xr, const void* __restrict__ xi,
                       bf16* __restrict__ Af, const int* __restrict__ flag) {
    int idx = blockIdx.x * 256 + threadIdx.x;
    if (idx >= NN * 1024) return;
    int r = idx >> 10, c = idx & 1023;
    float s = 0.f;
#pragma unroll
    for (int z = 0; z < 8; ++z)
        s += __bfloat162float(Pb[(size_t)z * NN * 1024 + idx]);
    size_t xoff = (size_t)r * CC + (c & (CC - 1));
    float xv;
    if (c < 512) xv = flag[0] ? __bfloat162float(((const bf16*)xr)[xoff]) : ((const float*)xr)[xoff];
    else         xv = flag[0] ? __bfloat162float(((const bf16*)xi)[xoff]) : ((const float*)xi)[xoff];
    float v = 2.f * s - xv;
    if (c < 512) Af[(size_t)(NN + r) * 1536 + 1024 + c] = __float2bfloat16(v);
    else         Af[(size_t)r * 1536 + 1024 + (c - 512)] = __float2bfloat16(-v);
}

// out = sum(4 partials) + bias
__global__ void epi3_k(const bf16* __restrict__ Pb, const void* __restrict__ bias,
                       void* __restrict__ out, const int* __restrict__ flag) {
    int idx = blockIdx.x * 256 + threadIdx.x;
    if (idx >= 4096 * CC) return;
    int c = idx & (CC - 1);
    float s = 0.f;
#pragma unroll
    for (int z = 0; z < 4; ++z)
        s += __bfloat162float(Pb[(size_t)z * 4096 * CC + idx]);
    float bb = flag[0] ? __bfloat162float(((const bf16*)bias)[c]) : ((const float*)bias)[c];
    float o = s + bb;
    if (flag[0]) ((bf16*)out)[idx] = __float2bfloat16(o);
    else         ((float*)out)[idx] = o;
}

// ---------------- split-K MFMA GEMM, BK=64, XOR-swizzled LDS ----------------
// Slice z writes its own bf16 partial: Pb[z*M*N + grow*N + gcol] (plain stores).
// 128x128 tile, 4 waves of 64x64, 32 MFMA per barrier pair.
__global__ __launch_bounds__(256) void gemm_sk_k(
    const bf16* __restrict__ Ab, const bf16* __restrict__ BTb,
    int M, int N, int K, int klen,
    bf16* __restrict__ Pb)
{
    __shared__ bf16 sA[128 * 64];
    __shared__ bf16 sB[128 * 64];
    int tid = threadIdx.x;
    int w = tid >> 6, lane = tid & 63;
    int row0 = blockIdx.y * 128, col0 = blockIdx.x * 128;
    int kbase = blockIdx.z * klen;
    int wave_m = (w >> 1) * 64, wave_n = (w & 1) * 64;
    int lm = lane & 15, lq = lane >> 4;

    int srow = lane >> 3;
    int sg   = lane & 7;
    int scol = (sg ^ srow) * 8;          // swizzled source column group
    const bf16 *gA[4], *gB[4];
    bf16 *lA[4], *lB[4];
#pragma unroll
    for (int i = 0; i < 4; ++i) {
        int c = w * 4 + i;
        int row = c * 8 + srow;
        gA[i] = Ab  + (size_t)(row0 + row) * K + kbase + scol;
        gB[i] = BTb + (size_t)(col0 + row) * K + kbase + scol;
        lA[i] = sA + c * 512 + lane * 8;
        lB[i] = sB + c * 512 + lane * 8;
    }

    floatx4 acc[4][4];
#pragma unroll
    for (int mf = 0; mf < 4; ++mf)
#pragma unroll
        for (int nf = 0; nf < 4; ++nf)
            acc[mf][nf] = (floatx4){0.f, 0.f, 0.f, 0.f};

    for (int kk = 0; kk < klen; kk += 64) {
        __syncthreads();
#pragma unroll
        for (int i = 0; i < 4; ++i) {
            gld16(gA[i] + kk, lA[i]);
            gld16(gB[i] + kk, lB[i]);
        }
        __syncthreads();
#pragma unroll
        for (int ks = 0; ks < 2; ++ks) {
            short8 af[4], bfv[4];
#pragma unroll
            for (int mf = 0; mf < 4; ++mf) {
                int row = wave_m + mf * 16 + lm;
                int g = (ks * 4 + lq) ^ (row & 7);
                af[mf] = *(const short8*)&sA[row * 64 + g * 8];
            }
#pragma unroll
            for (int nf = 0; nf < 4; ++nf) {
                int row = wave_n + nf * 16 + lm;
                int g = (ks * 4 + lq) ^ (row & 7);
                bfv[nf] = *(const short8*)&sB[row * 64 + g * 8];
            }
#pragma unroll
            for (int mf = 0; mf < 4; ++mf)
#pragma unroll
                for (int nf = 0; nf < 4; ++nf)
                    acc[mf][nf] = __builtin_amdgcn_mfma_f32_16x16x32_bf16(
                        af[mf], bfv[nf], acc[mf][nf], 0, 0, 0);
        }
    }

    bf16* slice = Pb + (size_t)blockIdx.z * M * N;
#pragma unroll
    for (int mf = 0; mf < 4; ++mf) {
#pragma unroll
        for (int nf = 0; nf < 4; ++nf) {
            int gcol = col0 + wave_n + nf * 16 + lm;
#pragma unroll
            for (int r = 0; r < 4; ++r) {
                int grow = row0 + wave_m + mf * 16 + lq * 4 + r;
                slice[(size_t)grow * N + gcol] = __float2bfloat16(acc[mf][nf][r]);
            }
        }
    }
}

// ---------------- launcher ----------------

extern "C" void kernel_launch(void* const* d_in, const int* in_sizes, int n_in,
                              void* d_out, int out_size, void* d_ws, size_t ws_size,
                              hipStream_t stream) {
    const void* Xr_in = d_in[0];
    const void* Xi_in = d_in[1];
    const void* edges = d_in[2];
    const void* q     = d_in[3];
    const void* ew    = d_in[4];
    const void* Wt    = d_in[5];
    const void* bias  = d_in[6];

    char* base = (char*)d_ws;
    const size_t MB = 1024 * 1024;
    float* A      = (float*)(base);                 // 16 MB during prep
    bf16*  Mpack  = (bf16*)(base + 16 * MB);        // 16 MB
    bf16*  Af     = (bf16*)(base + 32 * MB);        // 12 MB
    bf16*  BTb    = (bf16*)(base + 44 * MB);        // 8 MB
    bf16*  WT     = (bf16*)(base + 52 * MB);        // 1.5 MB
    float* rowsum = (float*)(base + 53 * MB + 512 * 1024);  // 8 KB
    float* colsum = (float*)(base + 53 * MB + 520 * 1024);  // 8 KB
    int*   flag   = (int*)  (base + 53 * MB + 528 * 1024);  // 8 B
    bf16*  Pb     = (bf16*)(base + 56 * MB);        // 32 MB: up to 8 bf16 partial slices

    detect_k<<<1, 256, 0, stream>>>((const unsigned int*)q, (const unsigned int*)edges,
                                    flag, colsum);
    hipMemsetAsync(A, 0, 16 * MB, stream);

    scatter_edges_k<<<NEDGE / 256, 256, 0, stream>>>(edges, ew, A, flag);
    sums_k<<<NN + 256, 256, 0, stream>>>(A, rowsum, colsum);
    build_Mpack_k<<<dim3(NN / 32, NN / 32), dim3(32, 32), 0, stream>>>(
        A, rowsum, colsum, q, Mpack, flag);

    pack_inputs_k<<<1792, 1024, 0, stream>>>(Xr_in, Xi_in, Wt, Af, BTb, WT, flag);

    // G1 (operand-swapped): PT[1024][2048] = XpackT @ Mpack^T, splitK=8 bf16 partials
    gemm_sk_k<<<dim3(NN / 128, 1024 / 128, 8), 256, 0, stream>>>(
        BTb, Mpack, 1024, NN, 4096, 512, Pb);
    packPT_k<<<dim3(2048 / 32, 512 / 32), dim3(32, 32), 0, stream>>>(Pb, BTb, Af);

    // G2: P = Mpack @ Z1packT^T, splitK=8 ; Af seg2 = 2*sum(P) - X
    gemm_sk_k<<<dim3(1024 / 128, NN / 128, 8), 256, 0, stream>>>(
        Mpack, BTb, NN, 1024, 4096, 512, Pb);
    epi2_k<<<(NN * 1024) / 256, 256, 0, stream>>>(Pb, Xr_in, Xi_in, Af, flag);

    // G3: P = Af @ WT^T (M=4096, N=512, K=1536, splitK=4) ; out = sum(P) + bias
    gemm_sk_k<<<dim3(CC / 128, 4096 / 128, 4), 256, 0, stream>>>(
        Af, WT, 4096, CC, 1536, 384, Pb);
    epi3_k<<<(4096 * CC) / 256, 256, 0, stream>>>(Pb, bias, d_out, flag);
}

// Round 14
// 198.609 us; speedup vs baseline: 1.0684x; 1.0684x over previous
//
#include <hip/hip_runtime.h>
#include <hip/hip_bf16.h>
#include <math.h>

#define NN 2048
#define CC 512
#define NEDGE 65536

typedef __hip_bfloat16 bf16;
typedef __attribute__((ext_vector_type(8))) short short8;
typedef __attribute__((ext_vector_type(4))) float floatx4;

static constexpr float TWO_PI_F = 6.2831853071795864769f;

// async global->LDS direct copy, 16 B per lane (dest = wave-uniform base + lane*16)
__device__ __forceinline__ void gld16(const void* g, void* l) {
    __builtin_amdgcn_global_load_lds(
        (const __attribute__((address_space(1))) unsigned int*)(unsigned long long)(uintptr_t)g,
        (__attribute__((address_space(3))) unsigned int*)(unsigned long long)(uintptr_t)l,
        16, 0, 0);
}

// ---------------- detector + colsum zero ----------------
__global__ __launch_bounds__(256) void detect_k(const unsigned int* __restrict__ qword,
                                                const unsigned int* __restrict__ ewords,
                                                int* __restrict__ flag,
                                                float* __restrict__ colsum) {
    int tid = threadIdx.x;
#pragma unroll
    for (int i = 0; i < 8; ++i) colsum[tid * 8 + i] = 0.f;
    if (tid < 64) {
        unsigned int w0 = ewords[2 * tid + 1];
        unsigned int w1 = ewords[128 + 2 * tid + 1];
        unsigned long long b = __ballot((w0 | w1) != 0u);
        if (tid == 0) {
            flag[0] = ((qword[0] & 0xFFFFu) == 0x3E80u) ? 1 : 0;
            flag[1] = (b == 0ull) ? 1 : 0;
        }
    }
}

// ---------------- prep kernels ----------------

__global__ void scatter_edges_k(const void* __restrict__ edges,
                                const void* __restrict__ w,
                                float* __restrict__ A,
                                const int* __restrict__ flag) {
    int e = blockIdx.x * 256 + threadIdx.x;
    if (e >= NEDGE) return;
    int f, t;
    if (flag[1]) {
        f = (int)((const long long*)edges)[e];
        t = (int)((const long long*)edges)[NEDGE + e];
    } else {
        f = ((const int*)edges)[e];
        t = ((const int*)edges)[NEDGE + e];
    }
    float wv = flag[0] ? __bfloat162float(((const bf16*)w)[e]) : ((const float*)w)[e];
    f &= (NN - 1); t &= (NN - 1);
    atomicAdd(&A[(size_t)f * NN + t], wv);
}

// Fused row+col sums. Blocks 0..2047: rowsum[i] (atomic-free LDS reduce).
// Blocks 2048..2303: 64-row col-stripe partials (8192 atomics, 4/address).
__global__ void sums_k(const float* __restrict__ A,
                       float* __restrict__ rowsum, float* __restrict__ colsum) {
    int b = blockIdx.x;
    if (b < NN) {
        float s = 0.f;
        for (int j = threadIdx.x; j < NN; j += 256) s += A[(size_t)b * NN + j];
        __shared__ float red[256];
        red[threadIdx.x] = s;
        __syncthreads();
        for (int off = 128; off > 0; off >>= 1) {
            if (threadIdx.x < off) red[threadIdx.x] += red[threadIdx.x + off];
            __syncthreads();
        }
        if (threadIdx.x == 0) rowsum[b] = red[0];
    } else {
        int bb = b - NN;                       // 0..255
        int col = (bb & 7) * 256 + threadIdx.x;
        int r0 = (bb >> 3) * 64;
        float s = 0.f;
        for (int r = r0; r < r0 + 64; ++r) s += A[(size_t)r * NN + col];
        atomicAdd(&colsum[col], s);
    }
}

// Mpack[i][j] = bf16(-cos(th)*A_norm), Mpack[i][2048+j] = bf16(sin(th)*A_norm)
__global__ __launch_bounds__(1024) void build_Mpack_k(
    const float* __restrict__ A,
    const float* __restrict__ rowsum, const float* __restrict__ colsum,
    const void* __restrict__ qp, bf16* __restrict__ Mpack,
    const int* __restrict__ flag) {
    __shared__ float tmir[32][33];
    int tx = threadIdx.x, ty = threadIdx.y;
    int j0 = blockIdx.x * 32, i0 = blockIdx.y * 32;
    tmir[ty][tx] = A[(size_t)(j0 + ty) * NN + i0 + tx];
    __syncthreads();
    int i = i0 + ty, j = j0 + tx;
    float qv = flag[0] ? __bfloat162float(((const bf16*)qp)[0]) : ((const float*)qp)[0];
    float di = 0.5f * (rowsum[i] + colsum[i]); di = (di == 0.f) ? 1.f : di;
    float dj = 0.5f * (rowsum[j] + colsum[j]); dj = (dj == 0.f) ? 1.f : dj;
    float a = A[(size_t)i * NN + j];
    float b = tmir[tx][ty];              // A[j][i]
    float an = rsqrtf(di) * (0.5f * (a + b)) * rsqrtf(dj);
    float th = TWO_PI_F * qv * (a - b);
    float sn, cs;
    sincosf(th, &sn, &cs);
    Mpack[(size_t)i * (2 * NN) + j]      = __float2bfloat16(-cs * an);
    Mpack[(size_t)i * (2 * NN) + NN + j] = __float2bfloat16(sn * an);
}

// Fused input pack: blocks 0..1023 = convert_X_BT (Af seg0 + BT X-pack);
// blocks 1024..1791 = WT transpose. Branch is block-uniform.
__global__ __launch_bounds__(1024) void pack_inputs_k(
    const void* __restrict__ xr, const void* __restrict__ xi,
    const void* __restrict__ Wt,
    bf16* __restrict__ Af, bf16* __restrict__ BT, bf16* __restrict__ WT,
    const int* __restrict__ flag) {
    __shared__ float t1[32][33];
    __shared__ float t2[32][33];
    int tid = threadIdx.x;
    int tx = tid & 31, ty = tid >> 5;
    int bx = blockIdx.x;
    int isbf = flag[0];
    if (bx < 1024) {
        int c0 = (bx & 15) * 32, r0 = (bx >> 4) * 32;
        size_t sidx = (size_t)(r0 + ty) * CC + c0 + tx;
        float fr, fi;
        if (isbf) {
            fr = __bfloat162float(((const bf16*)xr)[sidx]);
            fi = __bfloat162float(((const bf16*)xi)[sidx]);
        } else {
            fr = ((const float*)xr)[sidx];
            fi = ((const float*)xi)[sidx];
        }
        int r = r0 + ty, c = c0 + tx;
        Af[(size_t)r * 1536 + c]        = __float2bfloat16(-fi);
        Af[(size_t)(NN + r) * 1536 + c] = __float2bfloat16(fr);
        t1[ty][tx] = fr;
        t2[ty][tx] = fi;
        __syncthreads();
        float xrt = t1[tx][ty];   // Xr[r0+tx][c0+ty]
        float xit = t2[tx][ty];
        int n = c0 + ty, k = r0 + tx;
        BT[(size_t)n * 4096 + k]                = __float2bfloat16(xrt);
        BT[(size_t)(512 + n) * 4096 + k]        = __float2bfloat16(xit);
        BT[(size_t)n * 4096 + 2048 + k]         = __float2bfloat16(-xit);
        BT[(size_t)(512 + n) * 4096 + 2048 + k] = __float2bfloat16(xrt);
    } else {
        int bw = bx - 1024;               // 0..767
        int k0 = (bw % 48) * 32, o0 = (bw / 48) * 32;
        size_t sidx = (size_t)(k0 + ty) * CC + o0 + tx;
        t1[ty][tx] = isbf ? __bfloat162float(((const bf16*)Wt)[sidx])
                          : ((const float*)Wt)[sidx];
        __syncthreads();
        WT[(size_t)(o0 + ty) * 1536 + k0 + tx] = __float2bfloat16(t1[tx][ty]);
    }
}

// Fused PT consumer: sum 4 bf16 partials of PT [1024][2048], emit BT (G2 B-operand)
// and Af seg1. Grid (2048/32, 512/32), block (32,32).
__global__ __launch_bounds__(1024) void packPT_k(const bf16* __restrict__ Pb,
                                                 bf16* __restrict__ BT,
                                                 bf16* __restrict__ Af) {
    __shared__ float t1[32][33];
    __shared__ float t2[32][33];
    int tx = threadIdx.x, ty = threadIdx.y;
    int k0 = blockIdx.x * 32, n0 = blockIdx.y * 32;   // n0 in [0,512)
    size_t i1 = (size_t)(n0 + ty) * 2048 + k0 + tx;
    size_t i2 = (size_t)(512 + n0 + ty) * 2048 + k0 + tx;
    float s1 = 0.f, s2 = 0.f;
#pragma unroll
    for (int z = 0; z < 4; ++z) {
        s1 += __bfloat162float(Pb[(size_t)z * 1024 * 2048 + i1]);
        s2 += __bfloat162float(Pb[(size_t)z * 1024 * 2048 + i2]);
    }
    t1[ty][tx] = s1;
    t2[ty][tx] = s2;
    BT[(size_t)(n0 + ty) * 4096 + k0 + tx]              = __float2bfloat16(s1);
    BT[(size_t)(n0 + ty) * 4096 + 2048 + k0 + tx]       = __float2bfloat16(-s2);
    BT[(size_t)(512 + n0 + ty) * 4096 + k0 + tx]        = __float2bfloat16(s2);
    BT[(size_t)(512 + n0 + ty) * 4096 + 2048 + k0 + tx] = __float2bfloat16(s1);
    __syncthreads();
    Af[(size_t)(k0 + ty) * 1536 + 512 + n0 + tx]        = __float2bfloat16(-t2[tx][ty]);
    Af[(size_t)(NN + k0 + ty) * 1536 + 512 + n0 + tx]   = __float2bfloat16(t1[tx][ty]);
}

// Af seg2 = 2*sum(4 partials) - X (reads X inputs directly)
__global__ void epi2_k(const bf16* __restrict__ Pb,
                       const void* __restrict__ xr, const void* __restrict__ xi,
                       bf16* __restrict__ Af, const int* __restrict__ flag) {
    int idx = blockIdx.x * 256 + threadIdx.x;
    if (idx >= NN * 1024) return;
    int r = idx >> 10, c = idx & 1023;
    float s = 0.f;
#pragma unroll
    for (int z = 0; z < 4; ++z)
        s += __bfloat162float(Pb[(size_t)z * NN * 1024 + idx]);
    size_t xoff = (size_t)r * CC + (c & (CC - 1));
    float xv;
    if (c < 512) xv = flag[0] ? __bfloat162float(((const bf16*)xr)[xoff]) : ((const float*)xr)[xoff];
    else         xv = flag[0] ? __bfloat162float(((const bf16*)xi)[xoff]) : ((const float*)xi)[xoff];
    float v = 2.f * s - xv;
    if (c < 512) Af[(size_t)(NN + r) * 1536 + 1024 + c] = __float2bfloat16(v);
    else         Af[(size_t)r * 1536 + 1024 + (c - 512)] = __float2bfloat16(-v);
}

// out = sum(4 partials) + bias
__global__ void epi3_k(const bf16* __restrict__ Pb, const void* __restrict__ bias,
                       void* __restrict__ out, const int* __restrict__ flag) {
    int idx = blockIdx.x * 256 + threadIdx.x;
    if (idx >= 4096 * CC) return;
    int c = idx & (CC - 1);
    float s = 0.f;
#pragma unroll
    for (int z = 0; z < 4; ++z)
        s += __bfloat162float(Pb[(size_t)z * 4096 * CC + idx]);
    float bb = flag[0] ? __bfloat162float(((const bf16*)bias)[c]) : ((const float*)bias)[c];
    float o = s + bb;
    if (flag[0]) ((bf16*)out)[idx] = __float2bfloat16(o);
    else         ((float*)out)[idx] = o;
}

// ---------------- split-K MFMA GEMM, BK=64, XOR-swizzled LDS ----------------
// Slice z writes its own bf16 partial: Pb[z*M*N + grow*N + gcol] (plain stores).
// 128x128 tile, 4 waves of 64x64, 32 MFMA per barrier pair.
__global__ __launch_bounds__(256) void gemm_sk_k(
    const bf16* __restrict__ Ab, const bf16* __restrict__ BTb,
    int M, int N, int K, int klen,
    bf16* __restrict__ Pb)
{
    __shared__ bf16 sA[128 * 64];
    __shared__ bf16 sB[128 * 64];
    int tid = threadIdx.x;
    int w = tid >> 6, lane = tid & 63;
    int row0 = blockIdx.y * 128, col0 = blockIdx.x * 128;
    int kbase = blockIdx.z * klen;
    int wave_m = (w >> 1) * 64, wave_n = (w & 1) * 64;
    int lm = lane & 15, lq = lane >> 4;

    int srow = lane >> 3;
    int sg   = lane & 7;
    int scol = (sg ^ srow) * 8;          // swizzled source column group
    const bf16 *gA[4], *gB[4];
    bf16 *lA[4], *lB[4];
#pragma unroll
    for (int i = 0; i < 4; ++i) {
        int c = w * 4 + i;
        int row = c * 8 + srow;
        gA[i] = Ab  + (size_t)(row0 + row) * K + kbase + scol;
        gB[i] = BTb + (size_t)(col0 + row) * K + kbase + scol;
        lA[i] = sA + c * 512 + lane * 8;
        lB[i] = sB + c * 512 + lane * 8;
    }

    floatx4 acc[4][4];
#pragma unroll
    for (int mf = 0; mf < 4; ++mf)
#pragma unroll
        for (int nf = 0; nf < 4; ++nf)
            acc[mf][nf] = (floatx4){0.f, 0.f, 0.f, 0.f};

    for (int kk = 0; kk < klen; kk += 64) {
        __syncthreads();
#pragma unroll
        for (int i = 0; i < 4; ++i) {
            gld16(gA[i] + kk, lA[i]);
            gld16(gB[i] + kk, lB[i]);
        }
        __syncthreads();
#pragma unroll
        for (int ks = 0; ks < 2; ++ks) {
            short8 af[4], bfv[4];
#pragma unroll
            for (int mf = 0; mf < 4; ++mf) {
                int row = wave_m + mf * 16 + lm;
                int g = (ks * 4 + lq) ^ (row & 7);
                af[mf] = *(const short8*)&sA[row * 64 + g * 8];
            }
#pragma unroll
            for (int nf = 0; nf < 4; ++nf) {
                int row = wave_n + nf * 16 + lm;
                int g = (ks * 4 + lq) ^ (row & 7);
                bfv[nf] = *(const short8*)&sB[row * 64 + g * 8];
            }
#pragma unroll
            for (int mf = 0; mf < 4; ++mf)
#pragma unroll
                for (int nf = 0; nf < 4; ++nf)
                    acc[mf][nf] = __builtin_amdgcn_mfma_f32_16x16x32_bf16(
                        af[mf], bfv[nf], acc[mf][nf], 0, 0, 0);
        }
    }

    bf16* slice = Pb + (size_t)blockIdx.z * M * N;
#pragma unroll
    for (int mf = 0; mf < 4; ++mf) {
#pragma unroll
        for (int nf = 0; nf < 4; ++nf) {
            int gcol = col0 + wave_n + nf * 16 + lm;
#pragma unroll
            for (int r = 0; r < 4; ++r) {
                int grow = row0 + wave_m + mf * 16 + lq * 4 + r;
                slice[(size_t)grow * N + gcol] = __float2bfloat16(acc[mf][nf][r]);
            }
        }
    }
}

// ---------------- launcher ----------------

extern "C" void kernel_launch(void* const* d_in, const int* in_sizes, int n_in,
                              void* d_out, int out_size, void* d_ws, size_t ws_size,
                              hipStream_t stream) {
    const void* Xr_in = d_in[0];
    const void* Xi_in = d_in[1];
    const void* edges = d_in[2];
    const void* q     = d_in[3];
    const void* ew    = d_in[4];
    const void* Wt    = d_in[5];
    const void* bias  = d_in[6];

    char* base = (char*)d_ws;
    const size_t MB = 1024 * 1024;
    float* A      = (float*)(base);                 // 16 MB during prep
    bf16*  Mpack  = (bf16*)(base + 16 * MB);        // 16 MB
    bf16*  Af     = (bf16*)(base + 32 * MB);        // 12 MB
    bf16*  BTb    = (bf16*)(base + 44 * MB);        // 8 MB
    bf16*  WT     = (bf16*)(base + 52 * MB);        // 1.5 MB
    float* rowsum = (float*)(base + 53 * MB + 512 * 1024);  // 8 KB
    float* colsum = (float*)(base + 53 * MB + 520 * 1024);  // 8 KB
    int*   flag   = (int*)  (base + 53 * MB + 528 * 1024);  // 8 B
    bf16*  Pb     = (bf16*)(base + 56 * MB);        // 16 MB: 4 bf16 partial slices

    detect_k<<<1, 256, 0, stream>>>((const unsigned int*)q, (const unsigned int*)edges,
                                    flag, colsum);
    hipMemsetAsync(A, 0, 16 * MB, stream);

    scatter_edges_k<<<NEDGE / 256, 256, 0, stream>>>(edges, ew, A, flag);
    sums_k<<<NN + 256, 256, 0, stream>>>(A, rowsum, colsum);
    build_Mpack_k<<<dim3(NN / 32, NN / 32), dim3(32, 32), 0, stream>>>(
        A, rowsum, colsum, q, Mpack, flag);

    pack_inputs_k<<<1792, 1024, 0, stream>>>(Xr_in, Xi_in, Wt, Af, BTb, WT, flag);

    // G1 (operand-swapped): PT[1024][2048] = XpackT @ Mpack^T, splitK=4 bf16 partials
    gemm_sk_k<<<dim3(NN / 128, 1024 / 128, 4), 256, 0, stream>>>(
        BTb, Mpack, 1024, NN, 4096, 1024, Pb);
    packPT_k<<<dim3(2048 / 32, 512 / 32), dim3(32, 32), 0, stream>>>(Pb, BTb, Af);

    // G2: P = Mpack @ Z1packT^T, splitK=4 ; Af seg2 = 2*sum(P) - X
    gemm_sk_k<<<dim3(1024 / 128, NN / 128, 4), 256, 0, stream>>>(
        Mpack, BTb, NN, 1024, 4096, 1024, Pb);
    epi2_k<<<(NN * 1024) / 256, 256, 0, stream>>>(Pb, Xr_in, Xi_in, Af, flag);

    // G3: P = Af @ WT^T (M=4096, N=512, K=1536, splitK=4) ; out = sum(P) + bias
    gemm_sk_k<<<dim3(CC / 128, 4096 / 128, 4), 256, 0, stream>>>(
        Af, WT, 4096, CC, 1536, 384, Pb);
    epi3_k<<<(4096 * CC) / 256, 256, 0, stream>>>(Pb, bias, d_out, flag);
}

// Round 15
// 186.263 us; speedup vs baseline: 1.1392x; 1.0663x over previous
//
#include <hip/hip_runtime.h>
#include <hip/hip_bf16.h>
#include <math.h>

#define NN 2048
#define CC 512
#define NEDGE 65536

typedef __hip_bfloat16 bf16;
typedef __attribute__((ext_vector_type(8))) short short8;
typedef __attribute__((ext_vector_type(4))) float floatx4;

static constexpr float TWO_PI_F = 6.2831853071795864769f;

// async global->LDS direct copy, 16 B per lane (dest = wave-uniform base + lane*16)
__device__ __forceinline__ void gld16(const void* g, void* l) {
    __builtin_amdgcn_global_load_lds(
        (const __attribute__((address_space(1))) unsigned int*)(unsigned long long)(uintptr_t)g,
        (__attribute__((address_space(3))) unsigned int*)(unsigned long long)(uintptr_t)l,
        16, 0, 0);
}

// ---------------- detector ----------------
__global__ void detect_k(const unsigned int* __restrict__ qword,
                         const unsigned int* __restrict__ ewords,
                         int* __restrict__ flag) {
    int lane = threadIdx.x;           // 64 threads
    unsigned int w0 = ewords[2 * lane + 1];
    unsigned int w1 = ewords[128 + 2 * lane + 1];
    unsigned long long b = __ballot((w0 | w1) != 0u);
    if (lane == 0) {
        flag[0] = ((qword[0] & 0xFFFFu) == 0x3E80u) ? 1 : 0;   // bf16 mode
        flag[1] = (b == 0ull) ? 1 : 0;                          // int64 edges
    }
}

// ---------------- prep kernels ----------------

// Dual scatter: A[f][t] += w  and  AT[t][f] += w  (AT[i][j] == A[j][i])
__global__ void scatter_edges_k(const void* __restrict__ edges,
                                const void* __restrict__ w,
                                float* __restrict__ A, float* __restrict__ AT,
                                const int* __restrict__ flag) {
    int e = blockIdx.x * 256 + threadIdx.x;
    if (e >= NEDGE) return;
    int f, t;
    if (flag[1]) {
        f = (int)((const long long*)edges)[e];
        t = (int)((const long long*)edges)[NEDGE + e];
    } else {
        f = ((const int*)edges)[e];
        t = ((const int*)edges)[NEDGE + e];
    }
    float wv = flag[0] ? __bfloat162float(((const bf16*)w)[e]) : ((const float*)w)[e];
    f &= (NN - 1); t &= (NN - 1);
    atomicAdd(&A[(size_t)f * NN + t], wv);
    atomicAdd(&AT[(size_t)t * NN + f], wv);
}

// dinv[i] = rsqrt(deg_i), deg_i = 0.5*(sum_j A[i][j] + sum_j AT[i][j]); atomic-free
__global__ void dinv_k(const float* __restrict__ A, const float* __restrict__ AT,
                       float* __restrict__ dinv) {
    int i = blockIdx.x;
    float s = 0.f;
    for (int j = threadIdx.x; j < NN; j += 256)
        s += A[(size_t)i * NN + j] + AT[(size_t)i * NN + j];
    __shared__ float red[256];
    red[threadIdx.x] = s;
    __syncthreads();
    for (int off = 128; off > 0; off >>= 1) {
        if (threadIdx.x < off) red[threadIdx.x] += red[threadIdx.x + off];
        __syncthreads();
    }
    if (threadIdx.x == 0) {
        float d = 0.5f * red[0];
        if (d == 0.f) d = 1.f;
        dinv[i] = rsqrtf(d);
    }
}

// Fused input pack: blocks 0..1023 = Af seg0 (straight convert, no transpose);
// blocks 1024..1791 = WT transpose. Branch is block-uniform.
__global__ __launch_bounds__(1024) void pack_inputs_k(
    const void* __restrict__ xr, const void* __restrict__ xi,
    const void* __restrict__ Wt,
    bf16* __restrict__ Af, bf16* __restrict__ WT,
    const int* __restrict__ flag) {
    __shared__ float t1[32][33];
    int tid = threadIdx.x;
    int tx = tid & 31, ty = tid >> 5;
    int bx = blockIdx.x;
    int isbf = flag[0];
    if (bx < 1024) {
        int c0 = (bx & 15) * 32, r0 = (bx >> 4) * 32;
        size_t sidx = (size_t)(r0 + ty) * CC + c0 + tx;
        float fr, fi;
        if (isbf) {
            fr = __bfloat162float(((const bf16*)xr)[sidx]);
            fi = __bfloat162float(((const bf16*)xi)[sidx]);
        } else {
            fr = ((const float*)xr)[sidx];
            fi = ((const float*)xi)[sidx];
        }
        int r = r0 + ty, c = c0 + tx;
        Af[(size_t)r * 1536 + c]        = __float2bfloat16(-fi);
        Af[(size_t)(NN + r) * 1536 + c] = __float2bfloat16(fr);
    } else {
        int bw = bx - 1024;               // 0..767
        int k0 = (bw % 48) * 32, o0 = (bw / 48) * 32;
        size_t sidx = (size_t)(k0 + ty) * CC + o0 + tx;
        t1[ty][tx] = isbf ? __bfloat162float(((const bf16*)Wt)[sidx])
                          : ((const float*)Wt)[sidx];
        __syncthreads();
        WT[(size_t)(o0 + ty) * 1536 + k0 + tx] = __float2bfloat16(t1[tx][ty]);
    }
}

// ---------------- sparse complex row-SpMM ----------------
// One block per destination row i. Chunked 512-column windows; entries (s=a+b != 0)
// staged to LDS with on-the-fly M values (exact: duplicates impossible by construction).
// EPI=1: src = X inputs (dtype per flag) -> Z1c bf16 [2048][1024] ([Zr|Zi]) + Af seg1.
// EPI=2: src = Z1c -> Af seg2 = 2*acc - X.
template<int EPI>
__global__ __launch_bounds__(256) void spmm_k(
    const float* __restrict__ A, const float* __restrict__ AT,
    const float* __restrict__ dinv, const void* __restrict__ qp,
    const void* __restrict__ xr, const void* __restrict__ xi,
    const bf16* __restrict__ Z1in, bf16* __restrict__ Z1out,
    bf16* __restrict__ Af, const int* __restrict__ flag)
{
    __shared__ float s_mre[512], s_mim[512];
    __shared__ short s_col[512];
    __shared__ int s_cnt;
    int i = blockIdx.x;
    int tid = threadIdx.x;
    int isbf = flag[0];
    float qv = isbf ? __bfloat162float(((const bf16*)qp)[0]) : ((const float*)qp)[0];
    float dvi = dinv[i];
    float ar0 = 0.f, ai0 = 0.f, ar1 = 0.f, ai1 = 0.f;

    for (int c0 = 0; c0 < NN; c0 += 512) {
        if (tid == 0) s_cnt = 0;
        __syncthreads();
#pragma unroll
        for (int u = 0; u < 2; ++u) {
            int j = c0 + u * 256 + tid;                 // coalesced scan
            float a = A[(size_t)i * NN + j];
            float b = AT[(size_t)i * NN + j];           // == A[j][i]
            float s = a + b;
            if (s != 0.f) {                             // an==0 <=> M[i][j]==0
                int slot = atomicAdd(&s_cnt, 1);        // LDS atomic
                float an = dvi * (0.5f * s) * dinv[j];
                float th = TWO_PI_F * qv * (a - b);
                float sn, cs;
                sincosf(th, &sn, &cs);
                s_mre[slot] = -cs * an;
                s_mim[slot] = sn * an;
                s_col[slot] = (short)j;
            }
        }
        __syncthreads();
        int n = s_cnt;
        for (int s = 0; s < n; ++s) {
            float mre = s_mre[s], mim = s_mim[s];
            int j = s_col[s];
            float vr0, vr1, vi0, vi1;
            if (EPI == 1) {
                if (isbf) {
                    vr0 = __bfloat162float(((const bf16*)xr)[(size_t)j * CC + tid]);
                    vr1 = __bfloat162float(((const bf16*)xr)[(size_t)j * CC + tid + 256]);
                    vi0 = __bfloat162float(((const bf16*)xi)[(size_t)j * CC + tid]);
                    vi1 = __bfloat162float(((const bf16*)xi)[(size_t)j * CC + tid + 256]);
                } else {
                    vr0 = ((const float*)xr)[(size_t)j * CC + tid];
                    vr1 = ((const float*)xr)[(size_t)j * CC + tid + 256];
                    vi0 = ((const float*)xi)[(size_t)j * CC + tid];
                    vi1 = ((const float*)xi)[(size_t)j * CC + tid + 256];
                }
            } else {
                vr0 = __bfloat162float(Z1in[(size_t)j * 1024 + tid]);
                vr1 = __bfloat162float(Z1in[(size_t)j * 1024 + tid + 256]);
                vi0 = __bfloat162float(Z1in[(size_t)j * 1024 + 512 + tid]);
                vi1 = __bfloat162float(Z1in[(size_t)j * 1024 + 512 + tid + 256]);
            }
            ar0 += mre * vr0 - mim * vi0;  ai0 += mre * vi0 + mim * vr0;
            ar1 += mre * vr1 - mim * vi1;  ai1 += mre * vi1 + mim * vr1;
        }
        __syncthreads();
    }

    int c1 = tid, c2 = tid + 256;
    if (EPI == 1) {
        Z1out[(size_t)i * 1024 + c1]       = __float2bfloat16(ar0);
        Z1out[(size_t)i * 1024 + c2]       = __float2bfloat16(ar1);
        Z1out[(size_t)i * 1024 + 512 + c1] = __float2bfloat16(ai0);
        Z1out[(size_t)i * 1024 + 512 + c2] = __float2bfloat16(ai1);
        Af[(size_t)i * 1536 + 512 + c1]        = __float2bfloat16(-ai0);
        Af[(size_t)i * 1536 + 512 + c2]        = __float2bfloat16(-ai1);
        Af[(size_t)(NN + i) * 1536 + 512 + c1] = __float2bfloat16(ar0);
        Af[(size_t)(NN + i) * 1536 + 512 + c2] = __float2bfloat16(ar1);
    } else {
        float xrv0, xrv1, xiv0, xiv1;
        if (isbf) {
            xrv0 = __bfloat162float(((const bf16*)xr)[(size_t)i * CC + c1]);
            xrv1 = __bfloat162float(((const bf16*)xr)[(size_t)i * CC + c2]);
            xiv0 = __bfloat162float(((const bf16*)xi)[(size_t)i * CC + c1]);
            xiv1 = __bfloat162float(((const bf16*)xi)[(size_t)i * CC + c2]);
        } else {
            xrv0 = ((const float*)xr)[(size_t)i * CC + c1];
            xrv1 = ((const float*)xr)[(size_t)i * CC + c2];
            xiv0 = ((const float*)xi)[(size_t)i * CC + c1];
            xiv1 = ((const float*)xi)[(size_t)i * CC + c2];
        }
        float vre0 = 2.f * ar0 - xrv0, vre1 = 2.f * ar1 - xrv1;
        float vim0 = 2.f * ai0 - xiv0, vim1 = 2.f * ai1 - xiv1;
        Af[(size_t)(NN + i) * 1536 + 1024 + c1] = __float2bfloat16(vre0);
        Af[(size_t)(NN + i) * 1536 + 1024 + c2] = __float2bfloat16(vre1);
        Af[(size_t)i * 1536 + 1024 + c1]        = __float2bfloat16(-vim0);
        Af[(size_t)i * 1536 + 1024 + c2]        = __float2bfloat16(-vim1);
    }
}

// out = sum(4 partials) + bias
__global__ void epi3_k(const bf16* __restrict__ Pb, const void* __restrict__ bias,
                       void* __restrict__ out, const int* __restrict__ flag) {
    int idx = blockIdx.x * 256 + threadIdx.x;
    if (idx >= 4096 * CC) return;
    int c = idx & (CC - 1);
    float s = 0.f;
#pragma unroll
    for (int z = 0; z < 4; ++z)
        s += __bfloat162float(Pb[(size_t)z * 4096 * CC + idx]);
    float bb = flag[0] ? __bfloat162float(((const bf16*)bias)[c]) : ((const float*)bias)[c];
    float o = s + bb;
    if (flag[0]) ((bf16*)out)[idx] = __float2bfloat16(o);
    else         ((float*)out)[idx] = o;
}

// ---------------- split-K MFMA GEMM (G3 only), BK=64, XOR-swizzled LDS ----------------
__global__ __launch_bounds__(256) void gemm_sk_k(
    const bf16* __restrict__ Ab, const bf16* __restrict__ BTb,
    int M, int N, int K, int klen,
    bf16* __restrict__ Pb)
{
    __shared__ bf16 sA[128 * 64];
    __shared__ bf16 sB[128 * 64];
    int tid = threadIdx.x;
    int w = tid >> 6, lane = tid & 63;
    int row0 = blockIdx.y * 128, col0 = blockIdx.x * 128;
    int kbase = blockIdx.z * klen;
    int wave_m = (w >> 1) * 64, wave_n = (w & 1) * 64;
    int lm = lane & 15, lq = lane >> 4;

    int srow = lane >> 3;
    int sg   = lane & 7;
    int scol = (sg ^ srow) * 8;
    const bf16 *gA[4], *gB[4];
    bf16 *lA[4], *lB[4];
#pragma unroll
    for (int i = 0; i < 4; ++i) {
        int c = w * 4 + i;
        int row = c * 8 + srow;
        gA[i] = Ab  + (size_t)(row0 + row) * K + kbase + scol;
        gB[i] = BTb + (size_t)(col0 + row) * K + kbase + scol;
        lA[i] = sA + c * 512 + lane * 8;
        lB[i] = sB + c * 512 + lane * 8;
    }

    floatx4 acc[4][4];
#pragma unroll
    for (int mf = 0; mf < 4; ++mf)
#pragma unroll
        for (int nf = 0; nf < 4; ++nf)
            acc[mf][nf] = (floatx4){0.f, 0.f, 0.f, 0.f};

    for (int kk = 0; kk < klen; kk += 64) {
        __syncthreads();
#pragma unroll
        for (int i = 0; i < 4; ++i) {
            gld16(gA[i] + kk, lA[i]);
            gld16(gB[i] + kk, lB[i]);
        }
        __syncthreads();
#pragma unroll
        for (int ks = 0; ks < 2; ++ks) {
            short8 af[4], bfv[4];
#pragma unroll
            for (int mf = 0; mf < 4; ++mf) {
                int row = wave_m + mf * 16 + lm;
                int g = (ks * 4 + lq) ^ (row & 7);
                af[mf] = *(const short8*)&sA[row * 64 + g * 8];
            }
#pragma unroll
            for (int nf = 0; nf < 4; ++nf) {
                int row = wave_n + nf * 16 + lm;
                int g = (ks * 4 + lq) ^ (row & 7);
                bfv[nf] = *(const short8*)&sB[row * 64 + g * 8];
            }
#pragma unroll
            for (int mf = 0; mf < 4; ++mf)
#pragma unroll
                for (int nf = 0; nf < 4; ++nf)
                    acc[mf][nf] = __builtin_amdgcn_mfma_f32_16x16x32_bf16(
                        af[mf], bfv[nf], acc[mf][nf], 0, 0, 0);
        }
    }

    bf16* slice = Pb + (size_t)blockIdx.z * M * N;
#pragma unroll
    for (int mf = 0; mf < 4; ++mf) {
#pragma unroll
        for (int nf = 0; nf < 4; ++nf) {
            int gcol = col0 + wave_n + nf * 16 + lm;
#pragma unroll
            for (int r = 0; r < 4; ++r) {
                int grow = row0 + wave_m + mf * 16 + lq * 4 + r;
                slice[(size_t)grow * N + gcol] = __float2bfloat16(acc[mf][nf][r]);
            }
        }
    }
}

// ---------------- launcher ----------------

extern "C" void kernel_launch(void* const* d_in, const int* in_sizes, int n_in,
                              void* d_out, int out_size, void* d_ws, size_t ws_size,
                              hipStream_t stream) {
    const void* Xr_in = d_in[0];
    const void* Xi_in = d_in[1];
    const void* edges = d_in[2];
    const void* q     = d_in[3];
    const void* ew    = d_in[4];
    const void* Wt    = d_in[5];
    const void* bias  = d_in[6];

    char* base = (char*)d_ws;
    const size_t MB = 1024 * 1024;
    float* A    = (float*)(base);                  // 16 MB
    float* AT   = (float*)(base + 16 * MB);        // 16 MB (contiguous with A: one memset)
    bf16*  Af   = (bf16*)(base + 32 * MB);         // 12 MB
    bf16*  WT   = (bf16*)(base + 44 * MB);         // 1.5 MB
    bf16*  Z1c  = (bf16*)(base + 46 * MB);         // 4 MB (bf16 2048x1024 [Zr|Zi])
    float* dinv = (float*)(base + 50 * MB);        // 8 KB
    int*   flag = (int*)  (base + 50 * MB + 16 * 1024);   // 8 B
    bf16*  Pb   = (bf16*)(base + 56 * MB);         // 16 MB: 4 bf16 partial slices (G3)

    detect_k<<<1, 64, 0, stream>>>((const unsigned int*)q, (const unsigned int*)edges, flag);
    hipMemsetAsync(A, 0, 32 * MB, stream);         // A + AT in one fill

    scatter_edges_k<<<NEDGE / 256, 256, 0, stream>>>(edges, ew, A, AT, flag);
    dinv_k<<<NN, 256, 0, stream>>>(A, AT, dinv);
    pack_inputs_k<<<1792, 1024, 0, stream>>>(Xr_in, Xi_in, Wt, Af, WT, flag);

    // Z1 = M @ X  (sparse, M values on the fly) -> Z1c + Af seg1
    spmm_k<1><<<NN, 256, 0, stream>>>(A, AT, dinv, q, Xr_in, Xi_in,
                                      nullptr, Z1c, Af, flag);
    // Z2 = 2*M @ Z1 - X -> Af seg2
    spmm_k<2><<<NN, 256, 0, stream>>>(A, AT, dinv, q, Xr_in, Xi_in,
                                      Z1c, nullptr, Af, flag);

    // G3: P = Af @ WT^T (M=4096, N=512, K=1536, splitK=4) ; out = sum(P) + bias
    gemm_sk_k<<<dim3(CC / 128, 4096 / 128, 4), 256, 0, stream>>>(
        Af, WT, 4096, CC, 1536, 384, Pb);
    epi3_k<<<(4096 * CC) / 256, 256, 0, stream>>>(Pb, bias, d_out, flag);
}